// Round 1
// baseline (697.653 us; speedup 1.0000x reference)
//
#include <hip/hip_runtime.h>
#include <stdint.h>

typedef unsigned int u32;
typedef unsigned short u16;
typedef __attribute__((ext_vector_type(8))) short short8;
typedef __attribute__((ext_vector_type(4))) float f32x4;

// N=512, D=128 hardcoded. rows = N*N = 262144. per-channel matrix = 262144 elems.

__device__ __forceinline__ float bf2f(u16 v) {
  union { u32 u; float f; } c; c.u = ((u32)v) << 16; return c.f;
}
__device__ __forceinline__ u16 f2bf(float f) {
  union { float f; u32 u; } c; c.f = f;
  return (u16)((c.u + 0x7fffu + ((c.u >> 16) & 1u)) >> 16);
}
__device__ __forceinline__ float sigmoidf(float x) { return 1.0f / (1.0f + __expf(-x)); }

__device__ __forceinline__ void gload_lds16(const void* g, void* l) {
  __builtin_amdgcn_global_load_lds((const __attribute__((address_space(1))) u32*)g,
                                   (__attribute__((address_space(3))) u32*)l, 16, 0, 0);
}

// ---------------- K0: weight prep (fp32 -> bf16, interleave gate/proj) ----------------
// Wab[512][128]: row 2c = ab_gate_w[c], row 2c+1 = ab_proj_w[c].  Bab same interleave.
// Wout[256][128]: rows 0..127 = out_gate_w, 128..255 = out_proj_w. Bout same.
__global__ __launch_bounds__(256) void k0_prep(
    const float* __restrict__ abgw, const float* __restrict__ abgb,
    const float* __restrict__ abpw, const float* __restrict__ abpb,
    const float* __restrict__ ogw,  const float* __restrict__ ogb,
    const float* __restrict__ opw,  const float* __restrict__ opb,
    u16* __restrict__ Wab, float* __restrict__ Bab,
    u16* __restrict__ Wout, float* __restrict__ Bout)
{
  int idx = blockIdx.x * 256 + threadIdx.x;   // 0..65535
  int r = idx >> 7, k = idx & 127, c = r >> 1;
  float wv = (r & 1) ? abpw[c * 128 + k] : abgw[c * 128 + k];
  Wab[idx] = f2bf(wv);
  if (idx < 32768) {
    float wo = (idx < 16384) ? ogw[idx] : opw[idx - 16384];
    Wout[idx] = f2bf(wo);
  }
  if (idx < 512) Bab[idx] = (idx & 1) ? abpb[idx >> 1] : abgb[idx >> 1];
  if (idx < 256) Bout[idx] = (idx < 128) ? ogb[idx] : opb[idx - 128];
}

// ---------------- K1: LN(pair) + gate/proj GEMM + gating; write a_t/b_t [d][i][k] bf16 ----------------
// block = 256 thr (4 waves), 64 consecutive rows (same i coordinate, y0..y0+63).
__global__ __launch_bounds__(256) void k1_ln_proj(
    const float* __restrict__ pair, const float* __restrict__ mask2d,
    const u16* __restrict__ Wab, const float* __restrict__ Bab,
    u16* __restrict__ pairn, u16* __restrict__ a_t, u16* __restrict__ b_t,
    int write_pairn)
{
  __shared__ union { float tile[64][132]; u16 outT[256][66]; } sh;
  __shared__ u16 Aln[64][136];
  __shared__ float smask[64];

  const int tid  = threadIdx.x;
  const int lane = tid & 63;
  const int w    = tid >> 6;
  const int r0   = blockIdx.x * 64;
  const int x    = r0 >> 9;
  const int y0   = r0 & 511;

  // coalesced load of 64x128 fp32 tile
  #pragma unroll
  for (int it = 0; it < 32; ++it) {
    int idx = tid + it * 256;
    sh.tile[idx >> 7][idx & 127] = pair[r0 * 128 + idx];
  }
  if (tid < 64) smask[tid] = mask2d[r0 + tid];
  __syncthreads();

  // LayerNorm per row; 4 threads/row
  {
    const int row = tid >> 2, part = tid & 3;
    float s = 0.f, s2 = 0.f;
    #pragma unroll
    for (int ii = 0; ii < 32; ++ii) {
      float v = sh.tile[row][part + 4 * ii];
      s += v; s2 += v * v;
    }
    s  += __shfl_xor(s, 1);  s  += __shfl_xor(s, 2);
    s2 += __shfl_xor(s2, 1); s2 += __shfl_xor(s2, 2);
    float mu = s * 0.0078125f;
    float sc = rsqrtf(s2 * 0.0078125f - mu * mu + 1e-5f);
    #pragma unroll
    for (int ii = 0; ii < 32; ++ii) {
      int dc = part + 4 * ii;
      Aln[row][dc] = f2bf((sh.tile[row][dc] - mu) * sc);
    }
  }
  __syncthreads();

  if (write_pairn) {
    #pragma unroll
    for (int it = 0; it < 32; ++it) {
      int idx = tid + it * 256;
      pairn[r0 * 128 + idx] = Aln[idx >> 7][idx & 127];
    }
  }

  // GEMM 64 x 512 x 128: wave w covers cols [w*128, w*128+128), 2 passes of 64 cols
  #pragma unroll 1
  for (int p = 0; p < 2; ++p) {
    f32x4 acc[4][4];
    #pragma unroll
    for (int mf = 0; mf < 4; ++mf)
      #pragma unroll
      for (int nf = 0; nf < 4; ++nf) acc[mf][nf] = (f32x4){0.f, 0.f, 0.f, 0.f};

    #pragma unroll
    for (int kk = 0; kk < 4; ++kk) {
      short8 afr[4], bfr[4];
      #pragma unroll
      for (int mf = 0; mf < 4; ++mf)
        afr[mf] = *(const short8*)&Aln[mf * 16 + (lane & 15)][kk * 32 + (lane >> 4) * 8];
      #pragma unroll
      for (int nf = 0; nf < 4; ++nf) {
        int col = w * 128 + p * 64 + nf * 16 + (lane & 15);
        bfr[nf] = *(const short8*)(Wab + col * 128 + kk * 32 + (lane >> 4) * 8);
      }
      #pragma unroll
      for (int mf = 0; mf < 4; ++mf)
        #pragma unroll
        for (int nf = 0; nf < 4; ++nf)
          acc[mf][nf] = __builtin_amdgcn_mfma_f32_16x16x32_bf16(afr[mf], bfr[nf], acc[mf][nf], 0, 0, 0);
    }

    // epilogue: pair even(gate)/odd(proj) cols via shfl, gate, write transposed to LDS
    #pragma unroll
    for (int nf = 0; nf < 4; ++nf) {
      int col = w * 128 + p * 64 + nf * 16 + (lane & 15);
      float gb = Bab[col & ~1];
      float pb = Bab[col | 1];
      #pragma unroll
      for (int mf = 0; mf < 4; ++mf)
        #pragma unroll
        for (int rg = 0; rg < 4; ++rg) {
          float my = acc[mf][nf][rg];
          float ot = __shfl_xor(my, 1);
          if (!(lane & 1)) {
            int row = mf * 16 + (lane >> 4) * 4 + rg;
            float val = smask[row] * sigmoidf(my + gb) * (ot + pb);
            sh.outT[col >> 1][row] = f2bf(val);
          }
        }
    }
  }
  __syncthreads();

  // coalesced channel-major global write: a_t/b_t[d][x][y0+row]
  #pragma unroll
  for (int it = 0; it < 64; ++it) {
    int idx = tid + it * 256;
    int ch = idx >> 6, row = idx & 63;
    u16 v = sh.outT[ch][row];
    u16* dst = (ch < 128) ? (a_t + ch * 262144) : (b_t + (ch - 128) * 262144);
    dst[x * 512 + y0 + row] = v;
  }
}

// ---------------- K2: per-channel GEMM tri_d = A_d * B_d^T (m97 structure) ----------------
// grid = 128 channels * 16 tiles; block 256 thr, 128x128 tile, BK=64, global_load_lds staging.
__global__ __launch_bounds__(256) void k2_tri(
    const u16* __restrict__ a_t, const u16* __restrict__ b_t, u16* __restrict__ tri_t)
{
  __shared__ u16 Asub[128][64];
  __shared__ u16 Bsub[128][64];
  const int tid  = threadIdx.x;
  const int lane = tid & 63;
  const int w    = tid >> 6;
  const int wm   = w >> 1, wn = w & 1;
  const int bid  = blockIdx.x;
  const int dch  = bid >> 4;
  const int i0   = ((bid >> 2) & 3) * 128;
  const int j0   = (bid & 3) * 128;
  const u16* Ap = a_t + dch * 262144;
  const u16* Bp = b_t + dch * 262144;

  f32x4 acc[4][4];
  #pragma unroll
  for (int mf = 0; mf < 4; ++mf)
    #pragma unroll
    for (int nf = 0; nf < 4; ++nf) acc[mf][nf] = (f32x4){0.f, 0.f, 0.f, 0.f};

  for (int kk = 0; kk < 8; ++kk) {
    __syncthreads();
    #pragma unroll
    for (int it = 0; it < 4; ++it) {
      int c = it * 256 + tid;              // chunk of 16B; row = c>>3 (64 bf16/row)
      int row = c >> 3, ko = (c & 7) * 8;
      gload_lds16(Ap + (i0 + row) * 512 + kk * 64 + ko, ((u16*)Asub) + c * 8);
      gload_lds16(Bp + (j0 + row) * 512 + kk * 64 + ko, ((u16*)Bsub) + c * 8);
    }
    __syncthreads();
    #pragma unroll
    for (int ks = 0; ks < 2; ++ks) {
      short8 afr[4], bfr[4];
      #pragma unroll
      for (int mf = 0; mf < 4; ++mf)
        afr[mf] = *(const short8*)&Asub[wm * 64 + mf * 16 + (lane & 15)][ks * 32 + (lane >> 4) * 8];
      #pragma unroll
      for (int nf = 0; nf < 4; ++nf)
        bfr[nf] = *(const short8*)&Bsub[wn * 64 + nf * 16 + (lane & 15)][ks * 32 + (lane >> 4) * 8];
      #pragma unroll
      for (int mf = 0; mf < 4; ++mf)
        #pragma unroll
        for (int nf = 0; nf < 4; ++nf)
          acc[mf][nf] = __builtin_amdgcn_mfma_f32_16x16x32_bf16(afr[mf], bfr[nf], acc[mf][nf], 0, 0, 0);
    }
  }

  u16* Cp = tri_t + dch * 262144;
  #pragma unroll
  for (int mf = 0; mf < 4; ++mf)
    #pragma unroll
    for (int nf = 0; nf < 4; ++nf) {
      int col = wn * 64 + nf * 16 + (lane & 15);
      #pragma unroll
      for (int rg = 0; rg < 4; ++rg) {
        int row = wm * 64 + mf * 16 + (lane >> 4) * 4 + rg;
        Cp[(i0 + row) * 512 + j0 + col] = f2bf(acc[mf][nf][rg]);
      }
    }
}

// ---------------- K3: LN(tri) + out_gate/out_proj GEMMs + sigmoid gating ----------------
__global__ __launch_bounds__(256) void k3_out(
    const u16* __restrict__ tri_t, const u16* __restrict__ pairn,
    const float* __restrict__ pair,
    const u16* __restrict__ Wout, const float* __restrict__ Bout,
    float* __restrict__ out, int use_pairn)
{
  __shared__ u16 trin[64][136];
  __shared__ u16 pn[64][136];
  const int tid  = threadIdx.x;
  const int lane = tid & 63;
  const int w    = tid >> 6;
  const int r0   = blockIdx.x * 64;
  const int x    = r0 >> 9;
  const int y0   = r0 & 511;

  // gather tri (transpose channel-major -> row-major in LDS)
  #pragma unroll
  for (int it = 0; it < 32; ++it) {
    int dch = it * 4 + w;
    trin[lane][dch] = tri_t[dch * 262144 + x * 512 + y0 + lane];
  }
  if (use_pairn) {
    #pragma unroll
    for (int it = 0; it < 32; ++it) {
      int idx = tid + it * 256;
      pn[idx >> 7][idx & 127] = pairn[r0 * 128 + idx];
    }
  } else {
    // recompute LN(pair) from the fp32 input
    const int row = tid >> 2, part = tid & 3;
    float vals[32];
    float s = 0.f, s2 = 0.f;
    #pragma unroll
    for (int ii = 0; ii < 32; ++ii) {
      float v = pair[(r0 + row) * 128 + part + 4 * ii];
      vals[ii] = v; s += v; s2 += v * v;
    }
    s  += __shfl_xor(s, 1);  s  += __shfl_xor(s, 2);
    s2 += __shfl_xor(s2, 1); s2 += __shfl_xor(s2, 2);
    float mu = s * 0.0078125f;
    float sc = rsqrtf(s2 * 0.0078125f - mu * mu + 1e-5f);
    #pragma unroll
    for (int ii = 0; ii < 32; ++ii)
      pn[row][part + 4 * ii] = f2bf((vals[ii] - mu) * sc);
  }
  __syncthreads();

  // LayerNorm tri rows in place
  {
    const int row = tid >> 2, part = tid & 3;
    float vals[32];
    float s = 0.f, s2 = 0.f;
    #pragma unroll
    for (int ii = 0; ii < 32; ++ii) {
      float v = bf2f(trin[row][part + 4 * ii]);
      vals[ii] = v; s += v; s2 += v * v;
    }
    s  += __shfl_xor(s, 1);  s  += __shfl_xor(s, 2);
    s2 += __shfl_xor(s2, 1); s2 += __shfl_xor(s2, 2);
    float mu = s * 0.0078125f;
    float sc = rsqrtf(s2 * 0.0078125f - mu * mu + 1e-5f);
    #pragma unroll
    for (int ii = 0; ii < 32; ++ii)
      trin[row][part + 4 * ii] = f2bf((vals[ii] - mu) * sc);
  }
  __syncthreads();

  // two GEMMs 64x32x128 per wave: gate from pn, proj from trin
  f32x4 ag[4][2], ap[4][2];
  #pragma unroll
  for (int mf = 0; mf < 4; ++mf)
    #pragma unroll
    for (int nf = 0; nf < 2; ++nf) { ag[mf][nf] = (f32x4){0.f,0.f,0.f,0.f}; ap[mf][nf] = (f32x4){0.f,0.f,0.f,0.f}; }

  #pragma unroll
  for (int kk = 0; kk < 4; ++kk) {
    short8 fpn[4], ftr[4], bg[2], bp[2];
    #pragma unroll
    for (int mf = 0; mf < 4; ++mf) {
      fpn[mf] = *(const short8*)&pn  [mf * 16 + (lane & 15)][kk * 32 + (lane >> 4) * 8];
      ftr[mf] = *(const short8*)&trin[mf * 16 + (lane & 15)][kk * 32 + (lane >> 4) * 8];
    }
    #pragma unroll
    for (int nf = 0; nf < 2; ++nf) {
      int col = w * 32 + nf * 16 + (lane & 15);
      bg[nf] = *(const short8*)(Wout + col * 128 + kk * 32 + (lane >> 4) * 8);
      bp[nf] = *(const short8*)(Wout + (128 + col) * 128 + kk * 32 + (lane >> 4) * 8);
    }
    #pragma unroll
    for (int mf = 0; mf < 4; ++mf)
      #pragma unroll
      for (int nf = 0; nf < 2; ++nf) {
        ag[mf][nf] = __builtin_amdgcn_mfma_f32_16x16x32_bf16(fpn[mf], bg[nf], ag[mf][nf], 0, 0, 0);
        ap[mf][nf] = __builtin_amdgcn_mfma_f32_16x16x32_bf16(ftr[mf], bp[nf], ap[mf][nf], 0, 0, 0);
      }
  }

  #pragma unroll
  for (int nf = 0; nf < 2; ++nf) {
    int col = w * 32 + nf * 16 + (lane & 15);
    float gb = Bout[col], pb = Bout[128 + col];
    #pragma unroll
    for (int mf = 0; mf < 4; ++mf)
      #pragma unroll
      for (int rg = 0; rg < 4; ++rg) {
        int row = mf * 16 + (lane >> 4) * 4 + rg;
        out[(r0 + row) * 128 + col] = sigmoidf(ag[mf][nf][rg] + gb) * (ap[mf][nf][rg] + pb);
      }
  }
}

extern "C" void kernel_launch(void* const* d_in, const int* in_sizes, int n_in,
                              void* d_out, int out_size, void* d_ws, size_t ws_size,
                              hipStream_t stream)
{
  const float* pair   = (const float*)d_in[0];
  const float* mask2d = (const float*)d_in[1];
  const float* abpw   = (const float*)d_in[2];
  const float* abpb   = (const float*)d_in[3];
  const float* abgw   = (const float*)d_in[4];
  const float* abgb   = (const float*)d_in[5];
  const float* opw    = (const float*)d_in[6];
  const float* opb    = (const float*)d_in[7];
  const float* ogw    = (const float*)d_in[8];
  const float* ogb    = (const float*)d_in[9];

  char* ws = (char*)d_ws;
  u16*   tri_t = (u16*)ws;                                        // 64 MiB
  u16*   Wab   = (u16*)(ws + 67108864);                           // 128 KiB
  u16*   Wout  = (u16*)(ws + 67108864 + 131072);                  // 64 KiB
  float* Bab   = (float*)(ws + 67108864 + 131072 + 65536);        // 2 KiB
  float* Bout  = (float*)(ws + 67108864 + 131072 + 65536 + 2048); // 1 KiB
  size_t pairn_off = 67108864 + 131072 + 65536 + 2048 + 1024;
  u16*   pairn = (u16*)(ws + pairn_off);                          // 64 MiB (optional)
  int use_pairn = (ws_size >= pairn_off + 67108864) ? 1 : 0;

  // a_t/b_t (bf16, channel-major) live in d_out; dead before K3 overwrites it with the result
  u16* a_t = (u16*)d_out;
  u16* b_t = a_t + 33554432;

  k0_prep<<<dim3(256), dim3(256), 0, stream>>>(abgw, abgb, abpw, abpb, ogw, ogb, opw, opb,
                                               Wab, Bab, Wout, Bout);
  k1_ln_proj<<<dim3(4096), dim3(256), 0, stream>>>(pair, mask2d, Wab, Bab, pairn, a_t, b_t, use_pairn);
  k2_tri<<<dim3(2048), dim3(256), 0, stream>>>(a_t, b_t, tri_t);
  k3_out<<<dim3(4096), dim3(256), 0, stream>>>(tri_t, pairn, pair, Wout, Bout, (float*)d_out, use_pairn);
}